// Round 1
// baseline (1768.594 us; speedup 1.0000x reference)
//
#include <hip/hip_runtime.h>
#include <math.h>

#define B_   2
#define S_   2048
#define DIM_ 1024
#define H_   16
#define QD_  64
#define VD_  96
#define EPS_ 1e-8f

// ---------------------------------------------------------------------------
// RMSNorm: one block per row (B*S rows), 256 threads, float4 per thread.
// ---------------------------------------------------------------------------
__global__ __launch_bounds__(256) void rmsnorm_kernel(const float* __restrict__ x,
                                                      const float* __restrict__ w,
                                                      float* __restrict__ xn) {
    int row = blockIdx.x;
    int t = threadIdx.x;
    const float4* xr = (const float4*)(x + (size_t)row * DIM_);
    float4 v = xr[t];
    float ss = v.x * v.x + v.y * v.y + v.z * v.z + v.w * v.w;
#pragma unroll
    for (int off = 32; off > 0; off >>= 1) ss += __shfl_down(ss, off, 64);
    __shared__ float wsum[4];
    if ((t & 63) == 0) wsum[t >> 6] = ss;
    __syncthreads();
    float tot = wsum[0] + wsum[1] + wsum[2] + wsum[3];
    float scale = rsqrtf(tot * (1.0f / DIM_) + EPS_);
    const float4* wr = (const float4*)w;
    float4 wv = wr[t];
    float4 o;
    o.x = v.x * wv.x * scale;
    o.y = v.y * wv.y * scale;
    o.z = v.z * wv.z * scale;
    o.w = v.w * wv.w * scale;
    ((float4*)(xn + (size_t)row * DIM_))[t] = o;
}

// ---------------------------------------------------------------------------
// Generic fp32 GEMM: C[M x N] = A[M x K] @ B[K x N] (+ bias[n]).
// 64x64 tile, 256 threads, 4x4 per-thread register tile.
// Rows per thread: ty*4 + r (ty = t/16). Cols per thread: tx + 16*c (tx = t%16)
//   -> B reads from LDS are 16 distinct banks (conflict-free),
//      A reads are 4-addr broadcast b128 (free).
// M assumed multiple of 64 (always 4096 here); N guarded.
// ---------------------------------------------------------------------------
__global__ __launch_bounds__(256) void gemm64(const float* __restrict__ A, int lda,
                                              const float* __restrict__ Bm, int ldb,
                                              float* __restrict__ C, int ldc,
                                              const float* __restrict__ bias,
                                              int N, int K) {
    __shared__ float As[64][68];
    __shared__ float Bs[64][68];
    int t = threadIdx.x;
    int ty = t >> 4, tx = t & 15;
    int m0 = blockIdx.y * 64;
    int n0 = blockIdx.x * 64;
    float acc[4][4] = {};

    for (int k0 = 0; k0 < K; k0 += 64) {
#pragma unroll
        for (int c = 0; c < 4; ++c) {  // stage A 64x64
            int f = t + 256 * c;
            int r = f >> 4, q = f & 15;
            *(float4*)&As[r][q * 4] =
                *(const float4*)(A + (size_t)(m0 + r) * lda + k0 + q * 4);
        }
#pragma unroll
        for (int c = 0; c < 4; ++c) {  // stage B 64x64 (rows = k, cols = n)
            int f = t + 256 * c;
            int r = f >> 4, q = f & 15;
            int n = n0 + q * 4;
            float4 vb = make_float4(0.f, 0.f, 0.f, 0.f);
            if (n < N) vb = *(const float4*)(Bm + (size_t)(k0 + r) * ldb + n);
            *(float4*)&Bs[r][q * 4] = vb;
        }
        __syncthreads();
#pragma unroll 4
        for (int kc = 0; kc < 64; kc += 4) {
            float4 a[4];
            float bv4[4][4];
#pragma unroll
            for (int r = 0; r < 4; ++r) a[r] = *(const float4*)&As[ty * 4 + r][kc];
#pragma unroll
            for (int e = 0; e < 4; ++e)
#pragma unroll
                for (int c = 0; c < 4; ++c) bv4[e][c] = Bs[kc + e][tx + 16 * c];
#pragma unroll
            for (int r = 0; r < 4; ++r)
#pragma unroll
                for (int c = 0; c < 4; ++c) {
                    acc[r][c] = fmaf(a[r].x, bv4[0][c], acc[r][c]);
                    acc[r][c] = fmaf(a[r].y, bv4[1][c], acc[r][c]);
                    acc[r][c] = fmaf(a[r].z, bv4[2][c], acc[r][c]);
                    acc[r][c] = fmaf(a[r].w, bv4[3][c], acc[r][c]);
                }
        }
        __syncthreads();
    }

#pragma unroll
    for (int r = 0; r < 4; ++r) {
        int m = m0 + ty * 4 + r;
#pragma unroll
        for (int c = 0; c < 4; ++c) {
            int n = n0 + tx + 16 * c;
            if (n < N) {
                float v = acc[r][c];
                if (bias) v += bias[n];
                C[(size_t)m * ldc + n] = v;
            }
        }
    }
}

// ---------------------------------------------------------------------------
// RoPE: one thread per (chunk, pair). chunk = (b*S+s)*hc + h, pairs i=0..31.
// out[chunk*64 + i]      = x1*cos - x2*sin
// out[chunk*64 + 32 + i] = x1*sin + x2*cos   (x1 = in[2i], x2 = in[2i+1])
// freq[i] = 2048^(-i/31) = 2^(-11 i / 31); theta = s * freq.
// ---------------------------------------------------------------------------
__global__ __launch_bounds__(256) void rope_kernel(const float* __restrict__ in, int ldin,
                                                   float* __restrict__ out,
                                                   int hc, int total_pairs) {
    int p = blockIdx.x * 256 + threadIdx.x;
    if (p >= total_pairs) return;
    int i = p & 31;
    int chunk = p >> 5;
    int row = chunk / hc;  // b*S + s
    int h = chunk - row * hc;
    int s = row & (S_ - 1);
    const float* src = in + (size_t)row * ldin + h * 64;
    float2 x12 = *(const float2*)(src + 2 * i);
    float freq = exp2f((float)i * (-11.0f / 31.0f));
    float th = (float)s * freq;
    float sn, cs;
    sincosf(th, &sn, &cs);
    float* dst = out + (size_t)chunk * 64;
    dst[i] = x12.x * cs - x12.y * sn;
    dst[i + 32] = x12.x * sn + x12.y * cs;
}

// ---------------------------------------------------------------------------
// Attention: block = 64 query rows of one (b,h); loop over 32-wide key tiles.
// Softcap tanh bounds logits to [-5,5] -> softmax needs NO running max:
// single pass accumulating sum(exp) and sum(exp * v).
// Phase A: S = q.k^T (64x32) per tile, thread tile 4 rows x 2 cols.
// Phase B: ctx += P @ V, thread tile 4 rows x 6 cols (96 = 16*6).
// LDS ~52.7 KB -> 3 blocks/CU.
// ---------------------------------------------------------------------------
__global__ __launch_bounds__(256) void attn_kernel(const float* __restrict__ qr,  // (B,S,H,64)
                                                   const float* __restrict__ kr,  // (B,S,64)
                                                   const float* __restrict__ v,   // (B,S,96)
                                                   const float* __restrict__ bias,// (B,H,S,S)
                                                   float* __restrict__ ctx) {     // (B,S,H,96)
    __shared__ float qs[64][68];
    __shared__ float ks[32][68];
    __shared__ float vs[32][100];
    __shared__ float ps[64][36];
    __shared__ float rsp[64][17];
    __shared__ float rowsum[64];

    int t = threadIdx.x;
    int ty = t >> 4, tx = t & 15;
    int i0 = blockIdx.x * 64;
    int h = blockIdx.y;
    int b = blockIdx.z;

#pragma unroll
    for (int c = 0; c < 4; ++c) {  // stage q tile 64x64
        int f = t + 256 * c;
        int r = f >> 4, q = f & 15;
        *(float4*)&qs[r][q * 4] =
            *(const float4*)(qr + ((size_t)((b * S_ + i0 + r) * H_ + h)) * 64 + q * 4);
    }

    float acc[4][6] = {};
    float rsum_t[4] = {0.f, 0.f, 0.f, 0.f};
    const float* brow_base = bias + ((size_t)(b * H_ + h)) * S_ * S_;

    for (int j0 = 0; j0 < S_; j0 += 32) {
        __syncthreads();  // previous phase B done before restaging
#pragma unroll
        for (int c = 0; c < 2; ++c) {  // stage k tile 32x64
            int f = t + 256 * c;
            int r = f >> 4, q = f & 15;
            *(float4*)&ks[r][q * 4] =
                *(const float4*)(kr + (size_t)(b * S_ + j0 + r) * 64 + q * 4);
        }
#pragma unroll
        for (int c = 0; c < 3; ++c) {  // stage v tile 32x96
            int f = t + 256 * c;
            int r = f / 24, q = f - r * 24;
            *(float4*)&vs[r][q * 4] =
                *(const float4*)(v + (size_t)(b * S_ + j0 + r) * VD_ + q * 4);
        }
        __syncthreads();

        // Phase A: logits tile. rows ty*4+r, cols {tx, tx+16}
        float s[4][2] = {};
#pragma unroll 4
        for (int kc = 0; kc < 64; kc += 4) {
            float4 a[4], kb[2];
#pragma unroll
            for (int r = 0; r < 4; ++r) a[r] = *(const float4*)&qs[ty * 4 + r][kc];
#pragma unroll
            for (int c = 0; c < 2; ++c) kb[c] = *(const float4*)&ks[tx + 16 * c][kc];
#pragma unroll
            for (int r = 0; r < 4; ++r)
#pragma unroll
                for (int c = 0; c < 2; ++c) {
                    s[r][c] = fmaf(a[r].x, kb[c].x, s[r][c]);
                    s[r][c] = fmaf(a[r].y, kb[c].y, s[r][c]);
                    s[r][c] = fmaf(a[r].z, kb[c].z, s[r][c]);
                    s[r][c] = fmaf(a[r].w, kb[c].w, s[r][c]);
                }
        }
        // softcap + exp (no max subtraction needed: |logit| <= 5)
#pragma unroll
        for (int r = 0; r < 4; ++r) {
            const float* brow = brow_base + (size_t)(i0 + ty * 4 + r) * S_ + j0;
#pragma unroll
            for (int c = 0; c < 2; ++c) {
                int j = tx + 16 * c;
                float l = s[r][c] + brow[j];
                float e2 = __expf(0.4f * l);            // e^(2t), t = l/5
                float th = 1.0f - 2.0f / (e2 + 1.0f);   // tanh(t), inf-safe
                float p = __expf(5.0f * th);
                ps[ty * 4 + r][j] = p;
                rsum_t[r] += p;
            }
        }
        __syncthreads();

        // Phase B: ctx += P @ V. rows ty*4+r, cols tx*6+c
#pragma unroll 4
        for (int j = 0; j < 32; ++j) {
            float pv[4], vv[6];
#pragma unroll
            for (int r = 0; r < 4; ++r) pv[r] = ps[ty * 4 + r][j];
#pragma unroll
            for (int c = 0; c < 6; ++c) vv[c] = vs[j][tx * 6 + c];
#pragma unroll
            for (int r = 0; r < 4; ++r)
#pragma unroll
                for (int c = 0; c < 6; ++c) acc[r][c] = fmaf(pv[r], vv[c], acc[r][c]);
        }
    }

    // reduce row sums across the 16 tx-groups
#pragma unroll
    for (int r = 0; r < 4; ++r) rsp[ty * 4 + r][tx] = rsum_t[r];
    __syncthreads();
    if (t < 64) {
        float ssum = 0.f;
#pragma unroll
        for (int c = 0; c < 16; ++c) ssum += rsp[t][c];
        rowsum[t] = ssum;
    }
    __syncthreads();

#pragma unroll
    for (int r = 0; r < 4; ++r) {
        int i = i0 + ty * 4 + r;
        float rinv = 1.0f / rowsum[ty * 4 + r];
        float* crow = ctx + ((size_t)((b * S_ + i) * H_ + h)) * VD_;
#pragma unroll
        for (int c = 0; c < 6; ++c) crow[tx * 6 + c] = acc[r][c] * rinv;
    }
}

// ---------------------------------------------------------------------------
extern "C" void kernel_launch(void* const* d_in, const int* in_sizes, int n_in,
                              void* d_out, int out_size, void* d_ws, size_t ws_size,
                              hipStream_t stream) {
    (void)in_sizes; (void)n_in; (void)out_size; (void)ws_size;
    const float* x  = (const float*)d_in[0];
    const float* ab = (const float*)d_in[1];
    const float* rw = (const float*)d_in[2];
    const float* Wq = (const float*)d_in[3];
    const float* Wk = (const float*)d_in[4];
    const float* Wv = (const float*)d_in[5];
    const float* bv = (const float*)d_in[6];
    const float* Wo = (const float*)d_in[7];
    const float* bo = (const float*)d_in[8];
    float* out = (float*)d_out;
    float* ws = (float*)d_ws;

    const size_t R = (size_t)B_ * S_;  // 4096 rows
    float* xn  = ws;                    // R*1024 (reused as roped-q after GEMMs)
    float* qb  = xn  + R * DIM_;        // R*1024 (pre-rope q)
    float* kb  = qb  + R * DIM_;        // R*64   (pre-rope k)
    float* vb  = kb  + R * QD_;         // R*96
    float* krp = vb  + R * VD_;         // R*64   (roped k)
    float* ctx = krp + R * QD_;         // R*1536
    float* qrp = xn;                    // roped q aliases xn (xn dead after GEMMs)

    rmsnorm_kernel<<<dim3(R), 256, 0, stream>>>(x, rw, xn);

    // q/k/v projections
    gemm64<<<dim3(16, 64), 256, 0, stream>>>(xn, DIM_, Wq, H_ * QD_, qb, H_ * QD_,
                                             nullptr, H_ * QD_, DIM_);
    gemm64<<<dim3(1, 64), 256, 0, stream>>>(xn, DIM_, Wk, QD_, kb, QD_,
                                            nullptr, QD_, DIM_);
    gemm64<<<dim3(2, 64), 256, 0, stream>>>(xn, DIM_, Wv, VD_, vb, VD_,
                                            bv, VD_, DIM_);

    // RoPE
    rope_kernel<<<dim3((R * H_ * 32) / 256), 256, 0, stream>>>(qb, DIM_, qrp, H_,
                                                               (int)(R * H_ * 32));
    rope_kernel<<<dim3((R * 32) / 256), 256, 0, stream>>>(kb, QD_, krp, 1,
                                                          (int)(R * 32));

    // attention
    attn_kernel<<<dim3(S_ / 64, H_, B_), 256, 0, stream>>>(qrp, krp, vb, ab, ctx);

    // output projection
    gemm64<<<dim3(16, 64), 256, 0, stream>>>(ctx, H_ * VD_, Wo, DIM_, out, DIM_,
                                             bo, DIM_, H_ * VD_);
}

// Round 2
// 1068.500 us; speedup vs baseline: 1.6552x; 1.6552x over previous
//
#include <hip/hip_runtime.h>
#include <math.h>

#define B_   2
#define S_   2048
#define DIM_ 1024
#define H_   16
#define QD_  64
#define VD_  96
#define EPS_ 1e-8f

using half_t = _Float16;
using half8  = __attribute__((ext_vector_type(8))) _Float16;
using half4v = __attribute__((ext_vector_type(4))) _Float16;
using f32x4  = __attribute__((ext_vector_type(4))) float;

// ---------------------------------------------------------------------------
// RMSNorm: one block per row, 256 threads, float4 in, half4 out.
// ---------------------------------------------------------------------------
__global__ __launch_bounds__(256) void rmsnorm_h(const float* __restrict__ x,
                                                 const float* __restrict__ w,
                                                 half_t* __restrict__ xn) {
    int row = blockIdx.x;
    int t = threadIdx.x;
    float4 v = ((const float4*)(x + (size_t)row * DIM_))[t];
    float ss = v.x * v.x + v.y * v.y + v.z * v.z + v.w * v.w;
#pragma unroll
    for (int off = 32; off > 0; off >>= 1) ss += __shfl_down(ss, off, 64);
    __shared__ float wsum[4];
    if ((t & 63) == 0) wsum[t >> 6] = ss;
    __syncthreads();
    float tot = wsum[0] + wsum[1] + wsum[2] + wsum[3];
    float scale = rsqrtf(tot * (1.0f / DIM_) + EPS_);
    float4 wv = ((const float4*)w)[t];
    half4v o;
    o[0] = (half_t)(v.x * wv.x * scale);
    o[1] = (half_t)(v.y * wv.y * scale);
    o[2] = (half_t)(v.z * wv.z * scale);
    o[3] = (half_t)(v.w * wv.w * scale);
    ((half4v*)(xn + (size_t)row * DIM_))[t] = o;
}

// ---------------------------------------------------------------------------
// Tiled transpose + convert to fp16: out[C x R] = in[R x C]^T. R,C mult of 32.
// blockIdx.z batches (offset z*R*C both sides).
// ---------------------------------------------------------------------------
template <typename TIN>
__global__ __launch_bounds__(256) void transpose_cvt(const TIN* __restrict__ in,
                                                     half_t* __restrict__ out,
                                                     int R, int C) {
    __shared__ float tile[32][33];
    size_t zoff = (size_t)blockIdx.z * R * C;
    in += zoff;
    out += zoff;
    int tx = threadIdx.x & 31, ty = threadIdx.x >> 5;
#pragma unroll
    for (int i = 0; i < 32; i += 8) {
        int r = blockIdx.y * 32 + ty + i, c = blockIdx.x * 32 + tx;
        tile[ty + i][tx] = (float)in[(size_t)r * C + c];
    }
    __syncthreads();
#pragma unroll
    for (int i = 0; i < 32; i += 8) {
        int orow = blockIdx.x * 32 + ty + i, ocol = blockIdx.y * 32 + tx;
        out[(size_t)orow * R + ocol] = (half_t)tile[tx][ty + i];
    }
}

// ---------------------------------------------------------------------------
// fp16 MFMA GEMM: C[M x N] = A[M x K] @ BT[N x K]^T (+ bias). fp32 accum.
// 128x128 tile, BK=32, 4 waves in 2x2 of 64x64, 16x16x32_f16 MFMA.
// M mult of 128, K mult of 32; N guarded (64/96/1024 used).
// ---------------------------------------------------------------------------
template <typename OutT, bool BIAS>
__global__ __launch_bounds__(256) void gemm_h(const half_t* __restrict__ A,
                                              const half_t* __restrict__ BT,
                                              OutT* __restrict__ C,
                                              const float* __restrict__ bias,
                                              int M, int N, int K) {
    __shared__ half_t As[128][40];
    __shared__ half_t Bs[128][40];
    int t = threadIdx.x;
    int w = t >> 6, lane = t & 63, l15 = lane & 15, l4 = lane >> 4;
    int wm = (w >> 1) * 64, wn = (w & 1) * 64;
    int m0 = blockIdx.y * 128, n0 = blockIdx.x * 128;
    int r0 = t >> 2, off0 = (t & 3) * 8;
    f32x4 acc[4][4] = {};
    const half8 hz = {};

    for (int k0 = 0; k0 < K; k0 += 32) {
        __syncthreads();
        *(half8*)&As[r0][off0] = *(const half8*)(A + (size_t)(m0 + r0) * K + k0 + off0);
        *(half8*)&As[r0 + 64][off0] = *(const half8*)(A + (size_t)(m0 + r0 + 64) * K + k0 + off0);
        *(half8*)&Bs[r0][off0] =
            (n0 + r0 < N) ? *(const half8*)(BT + (size_t)(n0 + r0) * K + k0 + off0) : hz;
        *(half8*)&Bs[r0 + 64][off0] =
            (n0 + r0 + 64 < N) ? *(const half8*)(BT + (size_t)(n0 + r0 + 64) * K + k0 + off0) : hz;
        __syncthreads();
        half8 af[4], bf[4];
#pragma unroll
        for (int mt = 0; mt < 4; ++mt) af[mt] = *(const half8*)&As[wm + mt * 16 + l15][l4 * 8];
#pragma unroll
        for (int nt = 0; nt < 4; ++nt) bf[nt] = *(const half8*)&Bs[wn + nt * 16 + l15][l4 * 8];
#pragma unroll
        for (int mt = 0; mt < 4; ++mt)
#pragma unroll
            for (int nt = 0; nt < 4; ++nt)
                acc[mt][nt] =
                    __builtin_amdgcn_mfma_f32_16x16x32_f16(af[mt], bf[nt], acc[mt][nt], 0, 0, 0);
    }

#pragma unroll
    for (int mt = 0; mt < 4; ++mt)
#pragma unroll
        for (int nt = 0; nt < 4; ++nt) {
            int n = n0 + wn + nt * 16 + l15;
            if (n < N) {
#pragma unroll
                for (int reg = 0; reg < 4; ++reg) {
                    int m = m0 + wm + mt * 16 + l4 * 4 + reg;
                    float v = acc[mt][nt][reg];
                    if (BIAS) v += bias[n];
                    C[(size_t)m * N + n] = (OutT)v;
                }
            }
        }
}

// ---------------------------------------------------------------------------
// RoPE (fp16 in/out, fp32 math). One thread per (chunk, pair i<32).
// ---------------------------------------------------------------------------
__global__ __launch_bounds__(256) void rope_h(const half_t* __restrict__ in, int ldin,
                                              half_t* __restrict__ out,
                                              int hc, int total_pairs) {
    int p = blockIdx.x * 256 + threadIdx.x;
    if (p >= total_pairs) return;
    int i = p & 31;
    int chunk = p >> 5;
    int row = chunk / hc;
    int h = chunk - row * hc;
    int s = row & (S_ - 1);
    const half_t* src = in + (size_t)row * ldin + h * 64 + 2 * i;
    float x1 = (float)src[0], x2 = (float)src[1];
    float freq = exp2f((float)i * (-11.0f / 31.0f));
    float th = (float)s * freq;
    float sn, cs;
    sincosf(th, &sn, &cs);
    half_t* dst = out + (size_t)chunk * 64;
    dst[i] = (half_t)(x1 * cs - x2 * sn);
    dst[i + 32] = (half_t)(x1 * sn + x2 * cs);
}

// ---------------------------------------------------------------------------
// Attention (MFMA): block = 64 q-rows of one (b,h), 4 waves x 16 rows.
// j-loop step 64. QK^T via 16x16x32_f16 (Q frags in regs), softcap+exp fp32,
// P -> LDS fp32 -> cvt to A-frags, PV via MFMA with V^T tiles.
// Softcap bounds logits to [-5,5] -> no running max needed.
// LDS: ks 9.2KB + vs 13.8KB + ps 17.4KB = 40.4KB.
// ---------------------------------------------------------------------------
__global__ __launch_bounds__(256) void attn_mfma(const half_t* __restrict__ qh,  // (B,S,H,64)
                                                 const half_t* __restrict__ kh,  // (B,S,64)
                                                 const half_t* __restrict__ vt,  // (B,96,S)
                                                 const float* __restrict__ bias, // (B,H,S,S)
                                                 half_t* __restrict__ ctx) {     // (B,S,H*96)
    __shared__ half_t ks[64][72];
    __shared__ half_t vs[96][72];
    __shared__ float ps[4][16][68];

    int t = threadIdx.x;
    int w = t >> 6, lane = t & 63, l15 = lane & 15, l4 = lane >> 4;
    int i0 = blockIdx.x * 64, h = blockIdx.y, b = blockIdx.z;

    // Q A-fragments (K=64 -> two K=32 frags), held in registers for all j.
    const half_t* qbase =
        qh + (((size_t)(b * S_ + i0 + w * 16 + l15) * H_ + h) << 6) + l4 * 8;
    half8 qf0 = *(const half8*)qbase;
    half8 qf1 = *(const half8*)(qbase + 32);

    f32x4 cacc[6] = {};
    float rsum[4] = {0.f, 0.f, 0.f, 0.f};

    int sr = t >> 3, so = (t & 7) * 8;  // staging: row, halfs-offset (16B chunks)
    const float* bbase =
        bias + ((size_t)(b * H_ + h) * S_ + i0 + w * 16 + l4 * 4) * S_ + l15;

    for (int j0 = 0; j0 < S_; j0 += 64) {
        __syncthreads();
        {   // stage K tile (64 x 64) and V^T tile (96 x 64)
            const half_t* kg = kh + ((size_t)(b * S_ + j0) << 6);
            *(half8*)&ks[sr][so] = *(const half8*)(kg + ((size_t)sr << 6) + so);
            *(half8*)&ks[sr + 32][so] = *(const half8*)(kg + ((size_t)(sr + 32) << 6) + so);
            const half_t* vg = vt + (size_t)b * 96 * S_ + j0;
            *(half8*)&vs[sr][so] = *(const half8*)(vg + (size_t)sr * S_ + so);
            *(half8*)&vs[sr + 32][so] = *(const half8*)(vg + (size_t)(sr + 32) * S_ + so);
            *(half8*)&vs[sr + 64][so] = *(const half8*)(vg + (size_t)(sr + 64) * S_ + so);
        }
        __syncthreads();

        // QK^T + bias + softcap + exp; P (fp32) into per-wave LDS.
#pragma unroll
        for (int nt = 0; nt < 4; ++nt) {
            f32x4 s = {};
            half8 kb0 = *(const half8*)&ks[nt * 16 + l15][l4 * 8];
            half8 kb1 = *(const half8*)&ks[nt * 16 + l15][32 + l4 * 8];
            s = __builtin_amdgcn_mfma_f32_16x16x32_f16(qf0, kb0, s, 0, 0, 0);
            s = __builtin_amdgcn_mfma_f32_16x16x32_f16(qf1, kb1, s, 0, 0, 0);
            const float* bp = bbase + j0 + nt * 16;
#pragma unroll
            for (int reg = 0; reg < 4; ++reg) {
                float l = s[reg] + bp[(size_t)reg * S_];
                float e2 = __expf(0.4f * l);                              // e^(2l/5)
                float tnh = 1.0f - 2.0f * __builtin_amdgcn_rcpf(e2 + 1.0f); // tanh(l/5)
                float p = __expf(5.0f * tnh);
                rsum[reg] += p;
                ps[w][l4 * 4 + reg][nt * 16 + l15] = p;
            }
        }
        // per-wave only: no __syncthreads needed (compiler orders DS ops).

        // PV: A-frags from ps (cvt fp32->fp16), B-frags from vs.
        half8 af[2];
#pragma unroll
        for (int kf = 0; kf < 2; ++kf) {
            f32x4 p0 = *(const f32x4*)&ps[w][l15][kf * 32 + l4 * 8];
            f32x4 p1 = *(const f32x4*)&ps[w][l15][kf * 32 + l4 * 8 + 4];
            half8 a;
#pragma unroll
            for (int e = 0; e < 4; ++e) {
                a[e] = (half_t)p0[e];
                a[e + 4] = (half_t)p1[e];
            }
            af[kf] = a;
        }
#pragma unroll
        for (int nt = 0; nt < 6; ++nt) {
            half8 v0 = *(const half8*)&vs[nt * 16 + l15][l4 * 8];
            half8 v1 = *(const half8*)&vs[nt * 16 + l15][32 + l4 * 8];
            cacc[nt] = __builtin_amdgcn_mfma_f32_16x16x32_f16(af[0], v0, cacc[nt], 0, 0, 0);
            cacc[nt] = __builtin_amdgcn_mfma_f32_16x16x32_f16(af[1], v1, cacc[nt], 0, 0, 0);
        }
    }

    // rowsum: reduce across the 16 lanes sharing l4 (same 4 rows).
#pragma unroll
    for (int m = 1; m < 16; m <<= 1)
#pragma unroll
        for (int reg = 0; reg < 4; ++reg) rsum[reg] += __shfl_xor(rsum[reg], m, 64);
    float rinv[4];
#pragma unroll
    for (int reg = 0; reg < 4; ++reg) rinv[reg] = __builtin_amdgcn_rcpf(rsum[reg]);

#pragma unroll
    for (int nt = 0; nt < 6; ++nt)
#pragma unroll
        for (int reg = 0; reg < 4; ++reg) {
            int i = i0 + w * 16 + l4 * 4 + reg;
            ctx[((size_t)(b * S_ + i) * H_ + h) * VD_ + nt * 16 + l15] =
                (half_t)(cacc[nt][reg] * rinv[reg]);
        }
}

// ---------------------------------------------------------------------------
extern "C" void kernel_launch(void* const* d_in, const int* in_sizes, int n_in,
                              void* d_out, int out_size, void* d_ws, size_t ws_size,
                              hipStream_t stream) {
    (void)in_sizes; (void)n_in; (void)out_size; (void)ws_size;
    const float* x  = (const float*)d_in[0];
    const float* ab = (const float*)d_in[1];
    const float* rw = (const float*)d_in[2];
    const float* Wq = (const float*)d_in[3];
    const float* Wk = (const float*)d_in[4];
    const float* Wv = (const float*)d_in[5];
    const float* bv = (const float*)d_in[6];
    const float* Wo = (const float*)d_in[7];
    const float* bo = (const float*)d_in[8];
    float* out = (float*)d_out;

    const size_t R = (size_t)B_ * S_;  // 4096
    half_t* p = (half_t*)d_ws;
    half_t* xn_h = p;  p += R * DIM_;
    half_t* qb_h = p;  p += R * DIM_;
    half_t* q_h  = p;  p += R * DIM_;
    half_t* kb_h = p;  p += R * QD_;
    half_t* k_h  = p;  p += R * QD_;
    half_t* vb_h = p;  p += R * VD_;
    half_t* vtb  = p;  p += R * VD_;        // (B,96,S)
    half_t* ctx_h= p;  p += R * H_ * VD_;
    half_t* WqT  = p;  p += (size_t)DIM_ * (H_ * QD_);
    half_t* WkT  = p;  p += (size_t)DIM_ * QD_;
    half_t* WvT  = p;  p += (size_t)DIM_ * VD_;
    half_t* WoT  = p;  p += (size_t)(H_ * VD_) * DIM_;

    rmsnorm_h<<<dim3(R), 256, 0, stream>>>(x, rw, xn_h);

    // weight transposes (fp32 -> fp16, N x K layout)
    transpose_cvt<float><<<dim3(32, 32, 1), 256, 0, stream>>>(Wq, WqT, DIM_, H_ * QD_);
    transpose_cvt<float><<<dim3(2, 32, 1), 256, 0, stream>>>(Wk, WkT, DIM_, QD_);
    transpose_cvt<float><<<dim3(3, 32, 1), 256, 0, stream>>>(Wv, WvT, DIM_, VD_);
    transpose_cvt<float><<<dim3(32, 48, 1), 256, 0, stream>>>(Wo, WoT, H_ * VD_, DIM_);

    // projections
    gemm_h<half_t, false><<<dim3(8, 32), 256, 0, stream>>>(xn_h, WqT, qb_h, nullptr,
                                                           (int)R, H_ * QD_, DIM_);
    gemm_h<half_t, false><<<dim3(1, 32), 256, 0, stream>>>(xn_h, WkT, kb_h, nullptr,
                                                           (int)R, QD_, DIM_);
    gemm_h<half_t, true><<<dim3(1, 32), 256, 0, stream>>>(xn_h, WvT, vb_h, bv,
                                                          (int)R, VD_, DIM_);

    // RoPE
    rope_h<<<dim3((R * H_ * 32) / 256), 256, 0, stream>>>(qb_h, H_ * QD_, q_h, H_,
                                                          (int)(R * H_ * 32));
    rope_h<<<dim3((R * 32) / 256), 256, 0, stream>>>(kb_h, QD_, k_h, 1, (int)(R * 32));

    // V^T (B,S,96) -> (B,96,S)
    transpose_cvt<half_t><<<dim3(3, 64, 2), 256, 0, stream>>>(vb_h, vtb, S_, VD_);

    // attention
    attn_mfma<<<dim3(S_ / 64, H_, B_), 256, 0, stream>>>(q_h, k_h, vtb, ab, ctx_h);

    // output projection (fp32 out + bias)
    gemm_h<float, true><<<dim3(8, 32), 256, 0, stream>>>(ctx_h, WoT, out, bo,
                                                         (int)R, DIM_, H_ * VD_);
}